// Round 4
// baseline (76.995 us; speedup 1.0000x reference)
//
#include <hip/hip_runtime.h>

// QCQP quaternion loss. Per element: smallest eigenpair of 4x4 symmetric A
// via characteristic polynomial + monotone Newton from the Gershgorin lower
// bound, eigenvector = 4D cross product of 3 rows of A-lam*I (adjugate
// column, max-norm candidate). Loss = 8(1 - <v,qt>^2/|v|^2). Mean-reduce.
//
// R3: the R2 ILP=4 version spilled (VGPR_Count=32 for >100 live floats ->
// scratch traffic, VALUBusy stuck at 17%). Fix: __launch_bounds__(256,4)
// allows 128 VGPRs; ILP=2 fits without spill; ALL loads hoisted up front
// (12 in flight) so memory latency is paid once, not per-use.

#define ILP 2

__device__ __forceinline__ void cross4(const float* x, const float* y,
                                       const float* z, float* w) {
    float m01 = y[0]*z[1] - y[1]*z[0];
    float m02 = y[0]*z[2] - y[2]*z[0];
    float m03 = y[0]*z[3] - y[3]*z[0];
    float m12 = y[1]*z[2] - y[2]*z[1];
    float m13 = y[1]*z[3] - y[3]*z[1];
    float m23 = y[2]*z[3] - y[3]*z[2];
    w[0] =  (x[1]*m23 - x[2]*m13 + x[3]*m12);
    w[1] = -(x[0]*m23 - x[2]*m03 + x[3]*m02);
    w[2] =  (x[0]*m13 - x[1]*m03 + x[3]*m01);
    w[3] = -(x[0]*m12 - x[1]*m02 + x[2]*m01);
}

__device__ __forceinline__ float det3s(float p, float q, float r,
                                       float s, float t, float u) {
    return p*(s*u - t*t) - q*(q*u - r*t) + r*(q*t - r*s);
}

__global__ __launch_bounds__(256, 4) void qcqp_loss_kernel(
    const float* __restrict__ A_vec, const float* __restrict__ q_t,
    float* __restrict__ acc, unsigned int* __restrict__ cnt,
    float* __restrict__ out, int B, int nthreads, int nblocks)
{
    int tid = blockIdx.x * blockDim.x + threadIdx.x;

    // ---- phase 0: issue ALL loads up front (12 loads in flight) ----
    float2 va[ILP][5];
    float4 qt[ILP];
    bool   act[ILP];
    #pragma unroll
    for (int k = 0; k < ILP; ++k) {
        int i = tid + k * nthreads;
        act[k] = (i < B);
        int is = act[k] ? i : 0;
        const float* av = A_vec + (size_t)is * 10;
        va[k][0] = *(const float2*)(av + 0);
        va[k][1] = *(const float2*)(av + 2);
        va[k][2] = *(const float2*)(av + 4);
        va[k][3] = *(const float2*)(av + 6);
        va[k][4] = *(const float2*)(av + 8);
        qt[k]    = *(const float4*)(q_t + (size_t)is * 4);
    }

    // ---- phase 1: characteristic polynomial + Gershgorin bracket ----
    float m[ILP][10];
    float e1[ILP], e2[ILP], e3[ILP], e4[ILP];
    float lo[ILP], hi[ILP], lam[ILP];
    #pragma unroll
    for (int k = 0; k < ILP; ++k) {
        float m00 = -va[k][0].x, m01 = -va[k][0].y, m02 = -va[k][1].x, m03 = -va[k][1].y;
        float m11 = -va[k][2].x, m12 = -va[k][2].y, m13 = -va[k][3].x;
        float m22 = -va[k][3].y, m23 = -va[k][4].x, m33 = -va[k][4].y;
        m[k][0]=m00; m[k][1]=m01; m[k][2]=m02; m[k][3]=m03; m[k][4]=m11;
        m[k][5]=m12; m[k][6]=m13; m[k][7]=m22; m[k][8]=m23; m[k][9]=m33;

        e1[k] = m00 + m11 + m22 + m33;
        e2[k] = m00*m11 - m01*m01 + m00*m22 - m02*m02 + m00*m33 - m03*m03
              + m11*m22 - m12*m12 + m11*m33 - m13*m13 + m22*m33 - m23*m23;
        e3[k] = det3s(m11, m12, m13, m22, m23, m33)
              + det3s(m00, m02, m03, m22, m23, m33)
              + det3s(m00, m01, m03, m11, m13, m33)
              + det3s(m00, m01, m02, m11, m12, m22);
        float r0[4] = {m00, m01, m02, m03};
        float r1[4] = {m01, m11, m12, m13};
        float r2[4] = {m02, m12, m22, m23};
        float r3[4] = {m03, m13, m23, m33};
        float cw[4];
        cross4(r1, r2, r3, cw);
        e4[k] = r0[0]*cw[0] + r0[1]*cw[1] + r0[2]*cw[2] + r0[3]*cw[3];

        float s0 = fabsf(m01) + fabsf(m02) + fabsf(m03);
        float s1 = fabsf(m01) + fabsf(m12) + fabsf(m13);
        float s2 = fabsf(m02) + fabsf(m12) + fabsf(m23);
        float s3 = fabsf(m03) + fabsf(m13) + fabsf(m23);
        lo[k] = fminf(fminf(m00 - s0, m11 - s1), fminf(m22 - s2, m33 - s3)) - 1e-3f;
        hi[k] = fminf(fminf(m00, m11), fminf(m22, m33));
        lam[k] = lo[k];
    }

    // ---- phase 2: Newton, ILP chains interleaved ----
    #pragma unroll
    for (int it = 0; it < 12; ++it) {
        #pragma unroll
        for (int k = 0; k < ILP; ++k) {
            float l = lam[k];
            float p  = (((l - e1[k])*l + e2[k])*l - e3[k])*l + e4[k];
            float dp = ((4.f*l - 3.f*e1[k])*l + 2.f*e2[k])*l - e3[k];
            dp = fminf(dp, -1e-12f);
            l = l - p * __builtin_amdgcn_rcpf(dp);
            lam[k] = fminf(fmaxf(l, lo[k]), hi[k]);
        }
    }

    // ---- phase 3: eigenvector + loss ----
    float lsum = 0.f;
    #pragma unroll
    for (int k = 0; k < ILP; ++k) {
        float m00=m[k][0], m01=m[k][1], m02=m[k][2], m03=m[k][3], m11=m[k][4];
        float m12=m[k][5], m13=m[k][6], m22=m[k][7], m23=m[k][8], m33=m[k][9];
        float l = lam[k];
        float R0[4] = {m00 - l, m01, m02, m03};
        float R1[4] = {m01, m11 - l, m12, m13};
        float R2[4] = {m02, m12, m22 - l, m23};
        float R3[4] = {m03, m13, m23, m33 - l};
        float c0[4], c1[4], c2[4], c3[4];
        cross4(R1, R2, R3, c0);
        cross4(R0, R2, R3, c1);
        cross4(R0, R1, R3, c2);
        cross4(R0, R1, R2, c3);
        float n0 = c0[0]*c0[0] + c0[1]*c0[1] + c0[2]*c0[2] + c0[3]*c0[3];
        float n1 = c1[0]*c1[0] + c1[1]*c1[1] + c1[2]*c1[2] + c1[3]*c1[3];
        float n2 = c2[0]*c2[0] + c2[1]*c2[1] + c2[2]*c2[2] + c2[3]*c2[3];
        float n3 = c3[0]*c3[0] + c3[1]*c3[1] + c3[2]*c3[2] + c3[3]*c3[3];

        float bn = n0, w0 = c0[0], w1 = c0[1], w2 = c0[2], w3 = c0[3];
        bool b;
        b = n1 > bn; bn = b ? n1 : bn; w0 = b ? c1[0] : w0; w1 = b ? c1[1] : w1;
                     w2 = b ? c1[2] : w2; w3 = b ? c1[3] : w3;
        b = n2 > bn; bn = b ? n2 : bn; w0 = b ? c2[0] : w0; w1 = b ? c2[1] : w1;
                     w2 = b ? c2[2] : w2; w3 = b ? c2[3] : w3;
        b = n3 > bn; bn = b ? n3 : bn; w0 = b ? c3[0] : w0; w1 = b ? c3[1] : w1;
                     w2 = b ? c3[2] : w2; w3 = b ? c3[3] : w3;

        float d = w0*qt[k].x + w1*qt[k].y + w2*qt[k].z + w3*qt[k].w;
        float inv = __builtin_amdgcn_rcpf(fmaxf(bn, 1e-20f));
        float loss = 8.f * (bn - d*d) * inv;
        loss = fminf(fmaxf(loss, 0.f), 8.f);
        lsum += act[k] ? loss : 0.f;
    }

    // ---- block reduction: wave64 shuffle -> LDS -> one atomic per block ---
    #pragma unroll
    for (int off = 32; off > 0; off >>= 1)
        lsum += __shfl_down(lsum, off, 64);
    __shared__ float sm[4];
    int lane = threadIdx.x & 63, wid = threadIdx.x >> 6;
    if (lane == 0) sm[wid] = lsum;
    __syncthreads();
    if (threadIdx.x == 0) {
        atomicAdd(acc, sm[0] + sm[1] + sm[2] + sm[3]);
        __threadfence();
        unsigned int c = atomicAdd(cnt, 1u);
        if (c == (unsigned int)(nblocks - 1)) {
            float total = atomicAdd(acc, 0.f);
            out[0] = total / (float)B;
        }
    }
}

extern "C" void kernel_launch(void* const* d_in, const int* in_sizes, int n_in,
                              void* d_out, int out_size, void* d_ws, size_t ws_size,
                              hipStream_t stream)
{
    const float* A_vec = (const float*)d_in[0];
    const float* q_t   = (const float*)d_in[1];
    int B = in_sizes[0] / 10;
    float* acc = (float*)d_ws;
    unsigned int* cnt = (unsigned int*)((char*)d_ws + sizeof(float));

    hipMemsetAsync(d_ws, 0, 2 * sizeof(float), stream);
    int nthreads = (B + ILP - 1) / ILP;
    int nblocks = (nthreads + 255) / 256;
    qcqp_loss_kernel<<<nblocks, 256, 0, stream>>>(
        A_vec, q_t, acc, cnt, (float*)d_out, B, nthreads, nblocks);
}